// Round 10
// baseline (256.180 us; speedup 1.0000x reference)
//
#include <hip/hip_runtime.h>
#include <cstdint>
#include <cstddef>

// v: (B=16, L=16384, D=128) fp32.
// out[b, 2j+e, d] = (e==0 ? min : max)(v[b, p, d], v[b, p+1, d]),
//   p = (2j - s_d) mod L,  s_d = (d==0 ? 0 : 2d-2)  (always even, <= 252).
//
// Full-width design: 1 block/CU, 160 KB LDS ring of 320 full rows.
// Reads: dense sequential 64-row x 512B batches. Writes: dense full
// 512B output rows. Tests the DRAM-granularity theory for the ~3.8 TB/s
// plateau of all previous column-sliced (128B-granular) kernels.
#define L_DIM 16384
#define D_DIM 128
#define B_DIM 16

#define TPB 512
#define CHUNK 1024              // output rows per block
#define BATCH 64                // rows per batch (32 KB)
#define RING 320                // ring rows = 5 slots = 160 KB exactly
#define NB_OUT (CHUNK / BATCH)  // 16 output batches
// input batches = NB_OUT + 4 (skew halo 256 rows)

__global__ __launch_bounds__(TPB) void butterfly_dense_kernel(
    const float* __restrict__ v, float* __restrict__ out) {
  __shared__ float lds[RING * D_DIM];  // 160 KB -> 1 block/CU

  const int blk = blockIdx.x;           // 0..255, one per CU
  const int x = blk & 7, y = blk >> 3;  // XCD x owns chunks {2x, 2x+1}
  const int b  = y >> 1;                //   (halo rows shared in its L2)
  const int ch = 2 * x + (y & 1);
  const int R0  = ch * CHUNK;
  const int IN0 = R0 - 256 + L_DIM;     // unwrapped first input row (+L)

  const int t = threadIdx.x;

  const float* vb = v   + (size_t)b * (L_DIM * D_DIM);
  float*       ob = out + (size_t)b * (L_DIM * D_DIM);

  // Stage mapping: 32 float4 per 512B row; round u covers rows [16u,16u+16).
  const int srow = t >> 5;        // 0..15
  const int sc4  = (t & 31) * 4;  // float column of this thread's float4

  // ---- Prologue: load + LDS-write batches 0..3 (slots 0..3). ----
  float4 pre[16];
#pragma unroll
  for (int i = 0; i < 16; ++i) {
    const int bt = i >> 2, u = i & 3;
    const int row  = bt * BATCH + u * 16 + srow;       // 0..255
    const int grow = (IN0 + row) & (L_DIM - 1);
    pre[i] = *reinterpret_cast<const float4*>(vb + (size_t)grow * D_DIM + sc4);
  }
#pragma unroll
  for (int i = 0; i < 16; ++i) {
    const int bt = i >> 2, u = i & 3;
    const int row = bt * BATCH + u * 16 + srow;        // ring row == row
    *reinterpret_cast<float4*>(&lds[row * D_DIM + sc4]) = pre[i];
  }
  // Issue batch 4 into registers (in flight across the barrier).
  float4 rg[2][4];
#pragma unroll
  for (int u = 0; u < 4; ++u) {
    const int row  = 4 * BATCH + u * 16 + srow;
    const int grow = (IN0 + row) & (L_DIM - 1);
    rg[0][u] = *reinterpret_cast<const float4*>(vb + (size_t)grow * D_DIM + sc4);
  }
  asm volatile("s_waitcnt lgkmcnt(0)" ::: "memory");
  __builtin_amdgcn_s_barrier();

  // Compute-side constants. Thread -> (col d, pair-subgroup pj).
  const int d   = t & 127;
  const int pj  = t >> 7;                    // 0..3
  const int s_d = (d == 0) ? 0 : (2 * d - 2);
  const int offb = 256 - s_d + 2 * pj;       // in [4, 262]

#pragma unroll
  for (int w = 0; w < NB_OUT; ++w) {
    // Issue next input batch (w+5) into the other reg set; stays in
    // flight under this batch's compute (compiler emits exact vmcnt).
    if (w < NB_OUT - 1) {
#pragma unroll
      for (int u = 0; u < 4; ++u) {
        const int row  = (w + 5) * BATCH + u * 16 + srow;
        const int grow = (IN0 + row) & (L_DIM - 1);
        rg[(w + 1) & 1][u] =
            *reinterpret_cast<const float4*>(vb + (size_t)grow * D_DIM + sc4);
      }
    }
    // LDS-write batch w+4 into slot (w+4)%5 (overwrites batch w-1,
    // protected by the trailing barrier of iteration w-1).
    {
      const int slotbase = ((w + 4) % 5) * BATCH;  // compile-time
#pragma unroll
      for (int u = 0; u < 4; ++u) {
        const int row = slotbase + u * 16 + srow;
        *reinterpret_cast<float4*>(&lds[row * D_DIM + sc4]) = rg[w & 1][u];
      }
    }
    asm volatile("s_waitcnt lgkmcnt(0)" ::: "memory");  // writes visible
    __builtin_amdgcn_s_barrier();

    // Compute output batch w: rows [R0+64w, R0+64w+64), ALL 128 cols.
    // Ring now holds unwrapped input rows [64w, 64w+320); needed
    // indices base+offb+8s (+1) lie in [64w+4, 64w+319].  Dense stores.
    const int base = (BATCH * w) % RING;  // compile-time
    float* obw = ob + (size_t)(R0 + BATCH * w) * D_DIM + d;
#pragma unroll
    for (int s = 0; s < 8; ++s) {
      int q0 = base + offb + 8 * s;            // < 640
      q0 = (q0 >= RING) ? q0 - RING : q0;
      int q1 = q0 + 1;
      q1 = (q1 >= RING) ? q1 - RING : q1;
      const float a0 = lds[q0 * D_DIM + d];    // bank = d%32: 2-way, free
      const float a1 = lds[q1 * D_DIM + d];
      const int orow = 8 * s + 2 * pj;         // even row within batch
      obw[(size_t)orow * D_DIM]       = fminf(a0, a1);
      obw[(size_t)(orow + 1) * D_DIM] = fmaxf(a0, a1);
    }
    // This wave's ds_reads are retired (data-dep waits before stores);
    // barrier protects slots before next iteration's overwrite.
    asm volatile("s_waitcnt lgkmcnt(0)" ::: "memory");
    __builtin_amdgcn_s_barrier();
  }
}

extern "C" void kernel_launch(void* const* d_in, const int* in_sizes, int n_in,
                              void* d_out, int out_size, void* d_ws, size_t ws_size,
                              hipStream_t stream) {
  const float* v = (const float*)d_in[0];
  float* out = (float*)d_out;
  dim3 grid(256);   // (16 chunks) x (16 b), 1 block per CU
  dim3 block(TPB);
  butterfly_dense_kernel<<<grid, block, 0, stream>>>(v, out);
}